// Round 6
// baseline (590.306 us; speedup 1.0000x reference)
//
#include <hip/hip_runtime.h>

typedef unsigned short u16;
typedef __attribute__((ext_vector_type(8))) short bf16x8;   // 8 bf16 = 4 VGPRs (MFMA A/B frag)
typedef __attribute__((ext_vector_type(4))) short bf16x4;
typedef __attribute__((ext_vector_type(4))) float f32x4;    // MFMA C/D frag

__device__ __forceinline__ float bf2f(u16 u){ union { unsigned int i; float f; } v; v.i = ((unsigned int)u) << 16; return v.f; }
__device__ __forceinline__ u16 f2bf(float f){ union { float f; unsigned int i; } v; v.f = f; unsigned int r = v.i + 0x7fffu + ((v.i >> 16) & 1u); return (u16)(r >> 16); }

#define MFMA(a,b,c) __builtin_amdgcn_mfma_f32_16x16x32_bf16((a),(b),(c),0,0,0)

// async global->LDS, 16B per lane. LDS dest is wave-uniform base + lane*16.
__device__ __forceinline__ void gl_lds16(const u16* g, u16* l){
  __builtin_amdgcn_global_load_lds((const __attribute__((address_space(1))) unsigned int*)g,
                                   (__attribute__((address_space(3))) unsigned int*)l, 16, 0, 0);
}

// ---------------- Kernel 1: GroupNorm stats (mean, rstd) per (b, group) ----------------
__global__ __launch_bounds__(256) void k_gn_stats(const float* __restrict__ x, float* __restrict__ stats){
  const int bg = blockIdx.x;                       // 0..511
  const float4* p = (const float4*)(x + (size_t)bg * 65536);
  const int tid = threadIdx.x;
  float s = 0.f, sq = 0.f;
  for (int i = 0; i < 64; ++i){
    float4 v = p[tid + i*256];
    s += v.x + v.y + v.z + v.w;
    sq += v.x*v.x + v.y*v.y + v.z*v.z + v.w*v.w;
  }
#pragma unroll
  for (int d = 32; d > 0; d >>= 1){ s += __shfl_down(s, d, 64); sq += __shfl_down(sq, d, 64); }
  __shared__ float ls[4], lq[4];
  if ((tid & 63) == 0){ ls[tid>>6] = s; lq[tid>>6] = sq; }
  __syncthreads();
  if (tid == 0){
    float S = ls[0]+ls[1]+ls[2]+ls[3];
    float Q = lq[0]+lq[1]+lq[2]+lq[3];
    float mean = S * (1.f/65536.f);
    float var  = Q * (1.f/65536.f) - mean*mean;
    stats[bg*2]   = mean;
    stats[bg*2+1] = rsqrtf(var + 1e-5f);
  }
}

// ---------------- Kernel 1b: convert f32 weights -> bf16 (w_qkv then w_proj, packed) ----------------
__global__ __launch_bounds__(256) void k_conv_w(const float* __restrict__ wq, const float* __restrict__ wp,
                                                u16* __restrict__ wout){
  const int base = (blockIdx.x*256 + threadIdx.x) * 4;       // 1024 blocks -> 1,048,576 elems
  float4 v;
  if (base < 786432) v = *(const float4*)(wq + base);
  else               v = *(const float4*)(wp + (base - 786432));
  bf16x4 o;
  o[0] = (short)f2bf(v.x); o[1] = (short)f2bf(v.y); o[2] = (short)f2bf(v.z); o[3] = (short)f2bf(v.w);
  *(bf16x4*)(wout + base) = o;
}

// ---------------- Kernel 2: GN affine + transpose -> Xnt[b][l][c] (bf16) ----------------
__global__ __launch_bounds__(256) void k_gn_t(const float* __restrict__ x, const float* __restrict__ stats,
                                              const float* __restrict__ gamma, const float* __restrict__ beta,
                                              u16* __restrict__ xnt){
  __shared__ u16 tile[64*72];                      // [c][l], stride 72
  const int l0 = blockIdx.x*64, c0 = blockIdx.y*64, b = blockIdx.z;
  const int tid = threadIdx.x;
#pragma unroll
  for (int i = 0; i < 2; ++i){
    int v = tid + i*256; int cc = v >> 3, seg = v & 7;
    int c = c0 + cc;
    float mu = stats[(b*32 + (c>>4))*2], rs = stats[(b*32 + (c>>4))*2 + 1];
    float ga = gamma[c] * rs;
    float be = beta[c] - mu * ga;                  // (x-mu)*rs*g + b = x*ga + be
    const float* px = x + ((size_t)(b*512 + c))*4096 + l0 + seg*8;
    float4 a0 = *(const float4*)px;
    float4 a1 = *(const float4*)(px + 4);
    bf16x8 ov;
    ov[0]=(short)f2bf(a0.x*ga+be); ov[1]=(short)f2bf(a0.y*ga+be);
    ov[2]=(short)f2bf(a0.z*ga+be); ov[3]=(short)f2bf(a0.w*ga+be);
    ov[4]=(short)f2bf(a1.x*ga+be); ov[5]=(short)f2bf(a1.y*ga+be);
    ov[6]=(short)f2bf(a1.z*ga+be); ov[7]=(short)f2bf(a1.w*ga+be);
    *(bf16x8*)&tile[cc*72 + seg*8] = ov;
  }
  __syncthreads();
#pragma unroll
  for (int i = 0; i < 2; ++i){
    int v = tid + i*256; int ll = v >> 3, seg = v & 7;
    bf16x8 ov;
#pragma unroll
    for (int j = 0; j < 8; ++j) ov[j] = (short)tile[(seg*8 + j)*72 + ll];
    *(bf16x8*)(xnt + ((size_t)(b*4096 + l0 + ll))*512 + c0 + seg*8) = ov;
  }
}

// ---------------- Kernel 3: QKV GEMM, 256x256 tile, 8 waves, BK=32 3-buf counted-vmcnt ----------------
// D[m=l][n=o] = sum_c Xnt[l][c] * Wqkv[o][c] (+bias). 512 threads = 2(M) x 4(N) waves; per-wave
// output 128x64 = 8x4 frags (acc 128 VGPR). LDS: 3 x 32KB step buffers (A[256][32]+W[256][32]).
// 64B rows: bank_base=(row&1)*16+chunk*4 -> XOR key is row bits {1,2}: chunk = pc ^ ((row>>1)&3),
// applied source-side so linear global_load_lds writes land swizzled; ds_read_b128 conflict-free.
// Loop: wait own vmcnt(4) (stage cs landed, cs+1 in flight), s_barrier, stage cs+2, compute cs.
// reads/MFMA = 12/32 = 0.375 (vs 0.5 at 128x128): raises the LDS-pipe-bound MfmaUtil ceiling.
__global__ __launch_bounds__(512,2) void k_qkv(const u16* __restrict__ xnt, const u16* __restrict__ wq,
                                               const float* __restrict__ bq,
                                               u16* __restrict__ Qt, u16* __restrict__ Kt, u16* __restrict__ Vh){
  extern __shared__ __align__(16) u16 smem[];      // 98304 B = 3 x 16384-u16 buffers; epilogue bounce 128x264
  const int l0 = blockIdx.x*256, o0 = blockIdx.y*256, b = blockIdx.z;
  const int tid = threadIdx.x, wv = tid>>6, lane = tid&63, g = lane>>4, r = lane&15;
  const int wm = wv>>2, wn = wv&3;                 // 2 x 4 wave grid
  const u16* Ab = xnt + ((size_t)(b*4096 + l0))*512;
  const u16* Wb = wq  + (size_t)o0*512;
  // staging: chunk s = j*512 + tid; row = s>>2 (0..255 A, 256..511 W), phys chunk s&3,
  // logical chunk = (s&3) ^ ((row>>1)&3)
  const u16* gsrc[4];
  int ldoff[4];
#pragma unroll
  for (int j = 0; j < 4; ++j){
    const int s = j*512 + tid;
    const int row = s >> 2, pc = s & 3;
    const int lc = pc ^ ((row >> 1) & 3);
    gsrc[j] = ((row < 256) ? (Ab + (size_t)row*512) : (Wb + (size_t)(row - 256)*512)) + lc*8;
    ldoff[j] = (j*512 + wv*64)*8;                  // wave-uniform LDS chunk base (u16 units)
  }
  f32x4 acc[8][4];
#pragma unroll
  for (int mt = 0; mt < 8; ++mt)
#pragma unroll
    for (int nt = 0; nt < 4; ++nt) acc[mt][nt] = (f32x4){0.f,0.f,0.f,0.f};

#define STG3(bufo, c0) do { \
    u16* _bb = smem + (bufo); \
    _Pragma("unroll") \
    for (int _j = 0; _j < 4; ++_j) gl_lds16(gsrc[_j] + (c0), _bb + ldoff[_j]); \
  } while(0)

#define CMP3(bufo) do { \
    const u16* _cb = smem + (bufo); \
    const int _sw = (g ^ ((r >> 1) & 3)) * 8; \
    bf16x8 a_[8], w_[4]; \
    _Pragma("unroll") \
    for (int _mt = 0; _mt < 8; ++_mt) a_[_mt] = *(const bf16x8*)&_cb[(wm*128 + _mt*16 + r)*32 + _sw]; \
    _Pragma("unroll") \
    for (int _nt = 0; _nt < 4; ++_nt) w_[_nt] = *(const bf16x8*)&_cb[(256 + wn*64 + _nt*16 + r)*32 + _sw]; \
    __builtin_amdgcn_s_setprio(1); \
    _Pragma("unroll") \
    for (int _mt = 0; _mt < 8; ++_mt) \
      _Pragma("unroll") \
      for (int _nt = 0; _nt < 4; ++_nt) acc[_mt][_nt] = MFMA(a_[_mt], w_[_nt], acc[_mt][_nt]); \
    __builtin_amdgcn_s_setprio(0); \
  } while(0)

  STG3(0,      0);                                 // cs=0 -> buf0
  STG3(16384, 32);                                 // cs=1 -> buf1
  int cur = 0;
  for (int cs = 0; cs < 14; ++cs){
    asm volatile("s_waitcnt vmcnt(4)" ::: "memory");   // own stage(cs) landed; stage(cs+1) in flight
    __builtin_amdgcn_s_barrier();                      // all waves' stage(cs) visible; buf[(cs-1)%3] free
    __builtin_amdgcn_sched_barrier(0);
    int bn = cur + 2; if (bn >= 3) bn -= 3;
    STG3(bn*16384, (cs + 2)*32);
    CMP3(cur*16384);
    if (++cur == 3) cur = 0;
  }
  asm volatile("s_waitcnt vmcnt(4)" ::: "memory");
  __builtin_amdgcn_s_barrier();
  __builtin_amdgcn_sched_barrier(0);
  CMP3(cur*16384);                                 // cs=14
  if (++cur == 3) cur = 0;
  asm volatile("s_waitcnt vmcnt(0)" ::: "memory");
  __builtin_amdgcn_s_barrier();
  __builtin_amdgcn_sched_barrier(0);
  CMP3(cur*16384);                                 // cs=15
#undef STG3
#undef CMP3

  __syncthreads();                                 // last step's reads done; reuse smem for epilogue
  const int t   = blockIdx.y >> 1;                 // 0=Q 1=K 2=V
  const int cp0 = (blockIdx.y & 1)*256;            // c' base within tensor
  const int h   = blockIdx.x >> 1;                 // head = l0/512
  const int lh0 = (blockIdx.x & 1)*256;            // pos base within head
  const size_t bh = (size_t)(b*8 + h);
  if (t < 2){                                      // Q/K: dst[pos=l][c'=o], bounce [l 128][o 264]
    u16* dst = (t == 0) ? Qt : Kt;
#pragma unroll
    for (int p = 0; p < 2; ++p){                   // l-half == wm
      if (wm == p){
#pragma unroll
        for (int nt = 0; nt < 4; ++nt){
          const int ol = wn*64 + nt*16 + r;
          const float bi = bq[o0 + ol];
#pragma unroll
          for (int mt = 0; mt < 8; ++mt){
            const int ll = mt*16 + g*4;            // l-local within half
#pragma unroll
            for (int rr = 0; rr < 4; ++rr) smem[(ll + rr)*264 + ol] = f2bf(acc[mt][nt][rr] + bi);
          }
        }
      }
      __syncthreads();
#pragma unroll
      for (int i = 0; i < 8; ++i){
        int v = i*512 + tid; int row = v >> 5, seg = v & 31;
        bf16x8 d = *(const bf16x8*)&smem[row*264 + seg*8];
        *(bf16x8*)(dst + (bh*512 + lh0 + p*128 + row)*512 + cp0 + seg*8) = d;
      }
      __syncthreads();
    }
  } else {                                         // V: dst[c'=o][pos=l], bounce [o 128][l 264]
#pragma unroll
    for (int p = 0; p < 2; ++p){                   // o-half == wn>>1
      if ((wn >> 1) == p){
#pragma unroll
        for (int nt = 0; nt < 4; ++nt){
          const int ol = (wn & 1)*64 + nt*16 + r;  // o-local within half
          const float bi = bq[o0 + p*128 + ol];
#pragma unroll
          for (int mt = 0; mt < 8; ++mt){
            const int ll = wm*128 + mt*16 + g*4;
            bf16x4 pk;
#pragma unroll
            for (int rr = 0; rr < 4; ++rr) pk[rr] = (short)f2bf(acc[mt][nt][rr] + bi);
            *(bf16x4*)&smem[ol*264 + ll] = pk;
          }
        }
      }
      __syncthreads();
#pragma unroll
      for (int i = 0; i < 8; ++i){
        int v = i*512 + tid; int row = v >> 5, seg = v & 31;
        bf16x8 d = *(const bf16x8*)&smem[row*264 + seg*8];
        *(bf16x8*)(Vh + (bh*512 + cp0 + p*128 + row)*512 + lh0 + seg*8) = d;
      }
      __syncthreads();
    }
  }
}

// ---------------- Kernel 4: fused attention, QBLK=128, 512 threads, 8 waves ----------------
// Grid: 1D 512, XCD-chunked swizzle so the 4 q-tiles of each (b,h) land on one XCD (K/V L2 reuse).
// Phase 1: K[512][32]+Q[128][32] c-step tiles in LDS, 3 buffers x 40KB, depth-2 prefetch with
// counted s_waitcnt vmcnt(5) + raw s_barrier. 16B chunks XOR-swizzled with key (row>>1)&3 on the
// GLOBAL source side (64B rows: bank_base = (row&1)*16 + chunk*4 -> key must be row bits {1,2}).
// P[128][512] bf16 lives in LDS (128KB, aliases dead staging buffers), chunk swizzle ch^(q&7).
// Phase 2: V streamed global->reg (per-wave-exclusive c-range 64), barrier-free k-loop; first
// V fragments issued before the softmax-exit barrier.
__global__ __launch_bounds__(512,2) void k_attn(const u16* __restrict__ Qt, const u16* __restrict__ Kt,
                                                const u16* __restrict__ Vh, u16* __restrict__ At){
  extern __shared__ __align__(16) u16 smem[];      // 135168 B dynamic
  float* sMax = (float*)(smem + 65536);            // byte 131072: [q 128][wk 4]
  float* sSum = sMax + 512;                        // byte 133120: [q 128][wk 4]
  const int wgid = blockIdx.x;                     // 0..511; XCD-chunked remap (512 % 8 == 0 -> bijective)
  const int orig = (wgid & 7)*64 + (wgid >> 3);
  const int b = orig >> 5, h = (orig >> 2) & 7, q0 = (orig & 3) * 128;
  const int bh = b*8 + h;
  const int tid = threadIdx.x, wv = tid>>6, lane = tid&63, g = lane>>4, r = lane&15;
  const int wq = wv>>2, wk = wv&3;
  const size_t base = (size_t)bh * 262144;
  const u16* Qb = Qt + base + (size_t)q0*512;
  const u16* Kb = Kt + base;
  const u16* Vb = Vh + base;

  const u16* gsrc[5];
  int ldoff[5];
  {
    const int l4 = lane >> 2, pc = lane & 3;
#pragma unroll
    for (int j = 0; j < 5; ++j){
      const int i = wv*5 + j;
      const int row = ((i < 8) ? (i*16) : ((i-8)*16)) + l4;
      const u16* bp = (i < 8) ? (Qb + (size_t)row*512) : (Kb + (size_t)row*512);
      gsrc[j] = bp + ((pc ^ ((row >> 1) & 3)) * 8);
      ldoff[j] = i * 512;                          // u16 units; Q at [0,4096), K at [4096,20480)
    }
  }

  f32x4 s[4][8];
#pragma unroll
  for (int mt = 0; mt < 4; ++mt)
#pragma unroll
    for (int nt = 0; nt < 8; ++nt) s[mt][nt] = (f32x4){0.f,0.f,0.f,0.f};

  const int qswz = (g ^ ((r >> 1) & 3)) * 8;       // swizzled 16B-chunk offset within 64B row (u16)

#define STAGE_QK(bufbase, c0) do { \
    u16* _bb = (bufbase); \
    _Pragma("unroll") \
    for (int _j = 0; _j < 5; ++_j) gl_lds16(gsrc[_j] + (c0), _bb + ldoff[_j]); \
  } while(0)

#define QK_COMPUTE(bbp) do { \
    const u16* _cb = (bbp); \
    bf16x8 a_[4], kb_[8]; \
    _Pragma("unroll") \
    for (int _mt = 0; _mt < 4; ++_mt) a_[_mt] = *(const bf16x8*)&_cb[(wq*64 + _mt*16 + r)*32 + qswz]; \
    _Pragma("unroll") \
    for (int _nt = 0; _nt < 8; ++_nt) kb_[_nt] = *(const bf16x8*)&_cb[4096 + (wk*128 + _nt*16 + r)*32 + qswz]; \
    __builtin_amdgcn_s_setprio(1); \
    _Pragma("unroll") \
    for (int _mt = 0; _mt < 4; ++_mt) \
      _Pragma("unroll") \
      for (int _nt = 0; _nt < 8; ++_nt) s[_mt][_nt] = MFMA(a_[_mt], kb_[_nt], s[_mt][_nt]); \
    __builtin_amdgcn_s_setprio(0); \
  } while(0)

  // ---- Phase 1: S[q 128][k 512] = sum_c Q K^T, c-steps of 32, depth-2 pipeline over 3 buffers
  STAGE_QK(smem,         0);                       // cs=0 -> buf0
  STAGE_QK(smem + 20480, 32);                      // cs=1 -> buf1
  int bcur = 0;
  for (int cs = 0; cs < 15; ++cs){
    asm volatile("s_waitcnt vmcnt(5)" ::: "memory");   // own stage(cs) done; stage(cs+1) in flight
    __builtin_amdgcn_s_barrier();                      // all waves' stage(cs) visible; buf[(cs-1)%3] free
    __builtin_amdgcn_sched_barrier(0);
    if (cs < 14){
      int bn = bcur + 2; if (bn >= 3) bn -= 3;
      STAGE_QK(smem + bn*20480, (cs+2)*32);
    }
    QK_COMPUTE(smem + bcur*20480);
    if (++bcur == 3) bcur = 0;
  }
  asm volatile("s_waitcnt vmcnt(0)" ::: "memory");
  __builtin_amdgcn_s_barrier();
  __builtin_amdgcn_sched_barrier(0);
  QK_COMPUTE(smem + bcur*20480);                   // cs=15 (buf 0)

  // ---- softmax over k=512 (D layout: q = wq*64+mt*16+g*4+rr, k = wk*128+nt*16+r)
#pragma unroll
  for (int mt = 0; mt < 4; ++mt)
#pragma unroll
    for (int nt = 0; nt < 8; ++nt)
#pragma unroll
      for (int rr = 0; rr < 4; ++rr) s[mt][nt][rr] *= 0.125f;

  float mx[4][4];
#pragma unroll
  for (int mt = 0; mt < 4; ++mt)
#pragma unroll
    for (int rr = 0; rr < 4; ++rr){
      float m = s[mt][0][rr];
#pragma unroll
      for (int nt = 1; nt < 8; ++nt) m = fmaxf(m, s[mt][nt][rr]);
      m = fmaxf(m, __shfl_xor(m, 1, 64)); m = fmaxf(m, __shfl_xor(m, 2, 64));
      m = fmaxf(m, __shfl_xor(m, 4, 64)); m = fmaxf(m, __shfl_xor(m, 8, 64));
      mx[mt][rr] = m;
    }
  if (r == 0){
#pragma unroll
    for (int mt = 0; mt < 4; ++mt)
#pragma unroll
      for (int rr = 0; rr < 4; ++rr) sMax[(wq*64 + mt*16 + g*4 + rr)*4 + wk] = mx[mt][rr];
  }
  __syncthreads();
#pragma unroll
  for (int mt = 0; mt < 4; ++mt)
#pragma unroll
    for (int rr = 0; rr < 4; ++rr){
      float4 v = *(const float4*)&sMax[(wq*64 + mt*16 + g*4 + rr)*4];
      mx[mt][rr] = fmaxf(fmaxf(v.x, v.y), fmaxf(v.z, v.w));
    }
  float inv[4][4];
#pragma unroll
  for (int mt = 0; mt < 4; ++mt)
#pragma unroll
    for (int rr = 0; rr < 4; ++rr){
      float t = 0.f;
#pragma unroll
      for (int nt = 0; nt < 8; ++nt){
        float e = __expf(s[mt][nt][rr] - mx[mt][rr]);
        s[mt][nt][rr] = e; t += e;
      }
      t += __shfl_xor(t, 1, 64); t += __shfl_xor(t, 2, 64);
      t += __shfl_xor(t, 4, 64); t += __shfl_xor(t, 8, 64);
      inv[mt][rr] = t;                             // wave-partial sum for now
    }
  if (r == 0){
#pragma unroll
    for (int mt = 0; mt < 4; ++mt)
#pragma unroll
      for (int rr = 0; rr < 4; ++rr) sSum[(wq*64 + mt*16 + g*4 + rr)*4 + wk] = inv[mt][rr];
  }
  __syncthreads();
#pragma unroll
  for (int mt = 0; mt < 4; ++mt)
#pragma unroll
    for (int rr = 0; rr < 4; ++rr){
      float4 v = *(const float4*)&sSum[(wq*64 + mt*16 + g*4 + rr)*4];
      inv[mt][rr] = 1.f / (v.x + v.y + v.z + v.w);
    }
  // write P (bf16, chunk-swizzled ch^(q&7)) over the dead staging region
  {
    const int kx7 = r & 7, kbase = wk*16 + (r>>3);
#pragma unroll
    for (int mt = 0; mt < 4; ++mt)
#pragma unroll
      for (int rr = 0; rr < 4; ++rr){
        const int q = wq*64 + mt*16 + g*4 + rr;
        const int ro = q*512, qx = q & 7;
        const float iv = inv[mt][rr];
#pragma unroll
        for (int nt = 0; nt < 8; ++nt){
          const int ch = kbase + nt*2;             // k>>3
          smem[ro + ((ch ^ qx) * 8) + kx7] = f2bf(s[mt][nt][rr] * iv);
        }
      }
  }
  // early V prefetch: issue first fragments before the barrier so HBM latency hides under it
  const u16* Vw = Vb + (size_t)(wv*64 + r)*512 + g*8;
  bf16x8 vf[2][4];
#pragma unroll
  for (int mt = 0; mt < 4; ++mt) vf[0][mt] = *(const bf16x8*)(Vw + mt*8192);
  __syncthreads();

  // ---- Phase 2: A[c 512][q 128] = sum_k V[c][k] P[q][k]; wave owns c-range 64, barrier-free
  f32x4 o[4][8];
#pragma unroll
  for (int mt = 0; mt < 4; ++mt)
#pragma unroll
    for (int nt = 0; nt < 8; ++nt) o[mt][nt] = (f32x4){0.f,0.f,0.f,0.f};
#pragma unroll
  for (int kk = 0; kk < 16; ++kk){
    if (kk < 15){
#pragma unroll
      for (int mt = 0; mt < 4; ++mt) vf[(kk+1)&1][mt] = *(const bf16x8*)(Vw + mt*8192 + (kk+1)*32);
    }
    bf16x8 pp[8];
#pragma unroll
    for (int nt = 0; nt < 8; ++nt){
      const int q = nt*16 + r;
      pp[nt] = *(const bf16x8*)&smem[q*512 + (((kk*4 + g) ^ (r & 7)) * 8)];
    }
    __builtin_amdgcn_s_setprio(1);
#pragma unroll
    for (int mt = 0; mt < 4; ++mt)
#pragma unroll
      for (int nt = 0; nt < 8; ++nt) o[mt][nt] = MFMA(vf[kk&1][mt], pp[nt], o[mt][nt]);
    __builtin_amdgcn_s_setprio(0);
  }
  __syncthreads();                                  // all P reads done; reuse smem as At bounce

  // bounce o -> LDS [q][c] (same chunk swizzle), then coalesced copy out
#pragma unroll
  for (int mt = 0; mt < 4; ++mt){
    const int c = wv*64 + mt*16 + g*4;
    const int ch = c >> 3, cl = c & 7;
#pragma unroll
    for (int nt = 0; nt < 8; ++nt){
      const int q = nt*16 + r;
      bf16x4 pk;
#pragma unroll
      for (int rr = 0; rr < 4; ++rr) pk[rr] = (short)f2bf(o[mt][nt][rr]);
      *(bf16x4*)&smem[q*512 + ((ch ^ (r & 7)) * 8) + cl] = pk;
    }
  }
  __syncthreads();
  u16* Ad = At + ((size_t)(bh*512 + q0))*512;      // exactly this block's Q rows (in-place alias)
#pragma unroll
  for (int i = 0; i < 16; ++i){
    const int idx = tid + i*512, q = idx >> 6, ch = idx & 63;
    bf16x8 d = *(const bf16x8*)&smem[q*512 + ((ch ^ (q & 7)) * 8)];
    *(bf16x8*)(Ad + (size_t)q*512 + ch*8) = d;
  }
#undef STAGE_QK
#undef QK_COMPUTE
}

// ---------------- Kernel 5: proj GEMM, 256x256 tile, 8 waves, BK=32 pipeline + residual ----------------
__global__ __launch_bounds__(512,2) void k_proj(const u16* __restrict__ At, const u16* __restrict__ wp,
                                                const float* __restrict__ bpr, const float* __restrict__ x,
                                                float* __restrict__ out){
  extern __shared__ __align__(16) u16 smem[];      // 98304 B = 3 x 16384-u16 buffers; bounce 128x264
  const int l0 = blockIdx.x*256, o0 = blockIdx.y*256, b = blockIdx.z;
  const int tid = threadIdx.x, wv = tid>>6, lane = tid&63, g = lane>>4, r = lane&15;
  const int wm = wv>>2, wn = wv&3;
  const u16* Ab = At + ((size_t)(b*4096 + l0))*512;
  const u16* Wb = wp + (size_t)o0*512;
  const u16* gsrc[4];
  int ldoff[4];
#pragma unroll
  for (int j = 0; j < 4; ++j){
    const int s = j*512 + tid;
    const int row = s >> 2, pc = s & 3;
    const int lc = pc ^ ((row >> 1) & 3);
    gsrc[j] = ((row < 256) ? (Ab + (size_t)row*512) : (Wb + (size_t)(row - 256)*512)) + lc*8;
    ldoff[j] = (j*512 + wv*64)*8;
  }
  f32x4 acc[8][4];
#pragma unroll
  for (int mt = 0; mt < 8; ++mt)
#pragma unroll
    for (int nt = 0; nt < 4; ++nt) acc[mt][nt] = (f32x4){0.f,0.f,0.f,0.f};

#define STG5(bufo, c0) do { \
    u16* _bb = smem + (bufo); \
    _Pragma("unroll") \
    for (int _j = 0; _j < 4; ++_j) gl_lds16(gsrc[_j] + (c0), _bb + ldoff[_j]); \
  } while(0)

#define CMP5(bufo) do { \
    const u16* _cb = smem + (bufo); \
    const int _sw = (g ^ ((r >> 1) & 3)) * 8; \
    bf16x8 a_[8], w_[4]; \
    _Pragma("unroll") \
    for (int _mt = 0; _mt < 8; ++_mt) a_[_mt] = *(const bf16x8*)&_cb[(wm*128 + _mt*16 + r)*32 + _sw]; \
    _Pragma("unroll") \
    for (int _nt = 0; _nt < 4; ++_nt) w_[_nt] = *(const bf16x8*)&_cb[(256 + wn*64 + _nt*16 + r)*32 + _sw]; \
    __builtin_amdgcn_s_setprio(1); \
    _Pragma("unroll") \
    for (int _mt = 0; _mt < 8; ++_mt) \
      _Pragma("unroll") \
      for (int _nt = 0; _nt < 4; ++_nt) acc[_mt][_nt] = MFMA(a_[_mt], w_[_nt], acc[_mt][_nt]); \
    __builtin_amdgcn_s_setprio(0); \
  } while(0)

  STG5(0,      0);
  STG5(16384, 32);
  int cur = 0;
  for (int cs = 0; cs < 14; ++cs){
    asm volatile("s_waitcnt vmcnt(4)" ::: "memory");
    __builtin_amdgcn_s_barrier();
    __builtin_amdgcn_sched_barrier(0);
    int bn = cur + 2; if (bn >= 3) bn -= 3;
    STG5(bn*16384, (cs + 2)*32);
    CMP5(cur*16384);
    if (++cur == 3) cur = 0;
  }
  asm volatile("s_waitcnt vmcnt(4)" ::: "memory");
  __builtin_amdgcn_s_barrier();
  __builtin_amdgcn_sched_barrier(0);
  CMP5(cur*16384);                                 // cs=14
  if (++cur == 3) cur = 0;
  asm volatile("s_waitcnt vmcnt(0)" ::: "memory");
  __builtin_amdgcn_s_barrier();
  __builtin_amdgcn_sched_barrier(0);
  CMP5(cur*16384);                                 // cs=15
#undef STG5
#undef CMP5

  __syncthreads();
  // epilogue: out[b][o][l] = bf2f(acc+bias) + x; bounce [o 128][l 264] per o-half
#pragma unroll
  for (int p = 0; p < 2; ++p){                     // o-half == wn>>1
    if ((wn >> 1) == p){
#pragma unroll
      for (int nt = 0; nt < 4; ++nt){
        const int ol = (wn & 1)*64 + nt*16 + r;    // o-local within half
        const float bi = bpr[o0 + p*128 + ol];
#pragma unroll
        for (int mt = 0; mt < 8; ++mt){
          const int ll = wm*128 + mt*16 + g*4;
          bf16x4 pk;
#pragma unroll
          for (int rr = 0; rr < 4; ++rr) pk[rr] = (short)f2bf(acc[mt][nt][rr] + bi);
          *(bf16x4*)&smem[ol*264 + ll] = pk;
        }
      }
    }
    __syncthreads();
#pragma unroll
    for (int i = 0; i < 16; ++i){
      int v = i*512 + tid; int row = v >> 6, seg = v & 63;   // row=o-local, seg*4 = l-local
      bf16x4 d = *(const bf16x4*)&smem[row*264 + seg*4];
      const size_t gi = ((size_t)(b*512 + o0 + p*128 + row))*4096 + l0 + seg*4;
      float4 xv = *(const float4*)(x + gi);
      float4 ov;
      ov.x = bf2f((u16)d[0]) + xv.x;
      ov.y = bf2f((u16)d[1]) + xv.y;
      ov.z = bf2f((u16)d[2]) + xv.z;
      ov.w = bf2f((u16)d[3]) + xv.w;
      *(float4*)(out + gi) = ov;
    }
    __syncthreads();
  }
}

extern "C" void kernel_launch(void* const* d_in, const int* in_sizes, int n_in,
                              void* d_out, int out_size, void* d_ws, size_t ws_size,
                              hipStream_t stream) {
  (void)in_sizes; (void)n_in; (void)out_size; (void)ws_size;
  const float* x     = (const float*)d_in[0];
  const float* gamma = (const float*)d_in[1];
  const float* beta  = (const float*)d_in[2];
  const float* wqkv  = (const float*)d_in[3];
  const float* bqkv  = (const float*)d_in[4];
  const float* wproj = (const float*)d_in[5];
  const float* bproj = (const float*)d_in[6];
  float* out = (float*)d_out;
  char* ws = (char*)d_ws;

  float* stats = (float*)ws;                        // 8 KB
  u16* W16  = (u16*)(ws + 8192);                    // wqkv16 (786432) + wproj16 (262144)
  u16* Wq16 = W16;
  u16* Wp16 = W16 + 786432;
  u16* Qt = (u16*)(ws + 8192 + 2097152);            // 64 MiB  [b][h][pos][c]  (becomes At in place)
  u16* Kt = Qt + (size_t)33554432;                  // 64 MiB  [b][h][pos][c]
  u16* Vh = Kt + (size_t)33554432;                  // 64 MiB  [b][h][c][pos]
  u16* At = Qt;                                     // in-place alias (see k_attn)
  u16* Xnt = (u16*)d_out;                           // bf16 staging in d_out (dead before k_proj writes)

  static bool attn_attr = false;
  if (!attn_attr){
    hipFuncSetAttribute((const void*)k_attn, hipFuncAttributeMaxDynamicSharedMemorySize, 135168);
    hipFuncSetAttribute((const void*)k_qkv,  hipFuncAttributeMaxDynamicSharedMemorySize, 98304);
    hipFuncSetAttribute((const void*)k_proj, hipFuncAttributeMaxDynamicSharedMemorySize, 98304);
    attn_attr = true;
  }

  k_gn_stats<<<512, 256, 0, stream>>>(x, stats);
  k_conv_w<<<1024, 256, 0, stream>>>(wqkv, wproj, W16);
  k_gn_t<<<dim3(64,8,16), 256, 0, stream>>>(x, stats, gamma, beta, Xnt);
  k_qkv<<<dim3(16,6,16), 512, 98304, stream>>>(Xnt, Wq16, bqkv, Qt, Kt, Vh);
  k_attn<<<512, 512, 135168, stream>>>(Qt, Kt, Vh, At);
  k_proj<<<dim3(16,2,16), 512, 98304, stream>>>(At, Wp16, bproj, x, out);
}

// Round 7
// 581.041 us; speedup vs baseline: 1.0159x; 1.0159x over previous
//
#include <hip/hip_runtime.h>

typedef unsigned short u16;
typedef __attribute__((ext_vector_type(8))) short bf16x8;   // 8 bf16 = 4 VGPRs (MFMA A/B frag)
typedef __attribute__((ext_vector_type(4))) short bf16x4;
typedef __attribute__((ext_vector_type(4))) float f32x4;    // MFMA C/D frag

__device__ __forceinline__ float bf2f(u16 u){ union { unsigned int i; float f; } v; v.i = ((unsigned int)u) << 16; return v.f; }
__device__ __forceinline__ u16 f2bf(float f){ union { float f; unsigned int i; } v; v.f = f; unsigned int r = v.i + 0x7fffu + ((v.i >> 16) & 1u); return (u16)(r >> 16); }

#define MFMA(a,b,c) __builtin_amdgcn_mfma_f32_16x16x32_bf16((a),(b),(c),0,0,0)

// async global->LDS, 16B per lane. LDS dest is wave-uniform base + lane*16.
__device__ __forceinline__ void gl_lds16(const u16* g, u16* l){
  __builtin_amdgcn_global_load_lds((const __attribute__((address_space(1))) unsigned int*)g,
                                   (__attribute__((address_space(3))) unsigned int*)l, 16, 0, 0);
}

// ---------------- Kernel 1: GroupNorm stats (mean, rstd) per (b, group) ----------------
__global__ __launch_bounds__(256) void k_gn_stats(const float* __restrict__ x, float* __restrict__ stats){
  const int bg = blockIdx.x;                       // 0..511
  const float4* p = (const float4*)(x + (size_t)bg * 65536);
  const int tid = threadIdx.x;
  float s = 0.f, sq = 0.f;
  for (int i = 0; i < 64; ++i){
    float4 v = p[tid + i*256];
    s += v.x + v.y + v.z + v.w;
    sq += v.x*v.x + v.y*v.y + v.z*v.z + v.w*v.w;
  }
#pragma unroll
  for (int d = 32; d > 0; d >>= 1){ s += __shfl_down(s, d, 64); sq += __shfl_down(sq, d, 64); }
  __shared__ float ls[4], lq[4];
  if ((tid & 63) == 0){ ls[tid>>6] = s; lq[tid>>6] = sq; }
  __syncthreads();
  if (tid == 0){
    float S = ls[0]+ls[1]+ls[2]+ls[3];
    float Q = lq[0]+lq[1]+lq[2]+lq[3];
    float mean = S * (1.f/65536.f);
    float var  = Q * (1.f/65536.f) - mean*mean;
    stats[bg*2]   = mean;
    stats[bg*2+1] = rsqrtf(var + 1e-5f);
  }
}

// ---------------- Kernel 1b: convert f32 weights -> bf16 (w_qkv then w_proj, packed) ----------------
__global__ __launch_bounds__(256) void k_conv_w(const float* __restrict__ wq, const float* __restrict__ wp,
                                                u16* __restrict__ wout){
  const int base = (blockIdx.x*256 + threadIdx.x) * 4;       // 1024 blocks -> 1,048,576 elems
  float4 v;
  if (base < 786432) v = *(const float4*)(wq + base);
  else               v = *(const float4*)(wp + (base - 786432));
  bf16x4 o;
  o[0] = (short)f2bf(v.x); o[1] = (short)f2bf(v.y); o[2] = (short)f2bf(v.z); o[3] = (short)f2bf(v.w);
  *(bf16x4*)(wout + base) = o;
}

// ---------------- Kernel 2: GN affine + transpose -> Xnt[b][l][c] (bf16) ----------------
__global__ __launch_bounds__(256) void k_gn_t(const float* __restrict__ x, const float* __restrict__ stats,
                                              const float* __restrict__ gamma, const float* __restrict__ beta,
                                              u16* __restrict__ xnt){
  __shared__ u16 tile[64*72];                      // [c][l], stride 72
  const int l0 = blockIdx.x*64, c0 = blockIdx.y*64, b = blockIdx.z;
  const int tid = threadIdx.x;
#pragma unroll
  for (int i = 0; i < 2; ++i){
    int v = tid + i*256; int cc = v >> 3, seg = v & 7;
    int c = c0 + cc;
    float mu = stats[(b*32 + (c>>4))*2], rs = stats[(b*32 + (c>>4))*2 + 1];
    float ga = gamma[c] * rs;
    float be = beta[c] - mu * ga;                  // (x-mu)*rs*g + b = x*ga + be
    const float* px = x + ((size_t)(b*512 + c))*4096 + l0 + seg*8;
    float4 a0 = *(const float4*)px;
    float4 a1 = *(const float4*)(px + 4);
    bf16x8 ov;
    ov[0]=(short)f2bf(a0.x*ga+be); ov[1]=(short)f2bf(a0.y*ga+be);
    ov[2]=(short)f2bf(a0.z*ga+be); ov[3]=(short)f2bf(a0.w*ga+be);
    ov[4]=(short)f2bf(a1.x*ga+be); ov[5]=(short)f2bf(a1.y*ga+be);
    ov[6]=(short)f2bf(a1.z*ga+be); ov[7]=(short)f2bf(a1.w*ga+be);
    *(bf16x8*)&tile[cc*72 + seg*8] = ov;
  }
  __syncthreads();
#pragma unroll
  for (int i = 0; i < 2; ++i){
    int v = tid + i*256; int ll = v >> 3, seg = v & 7;
    bf16x8 ov;
#pragma unroll
    for (int j = 0; j < 8; ++j) ov[j] = (short)tile[(seg*8 + j)*72 + ll];
    *(bf16x8*)(xnt + ((size_t)(b*4096 + l0 + ll))*512 + c0 + seg*8) = ov;
  }
}

// ---------------- Kernel 3: QKV GEMM, 256x256 tile, 8-phase m201-style schedule ----------------
// 512 threads = 2(M) x 4(N) waves; per-wave C = 128x64 = 8x4 frags (128 VGPR).
// LDS 128KB = 2 K-tile (BK=64) buffers x 64KB; each buffer = 4 contiguous 16KB units:
//   [A-kh0][A-kh1][W-kh0][W-kh1]  (kh = K-half, 32 cols; 256 rows x 4 chunks x 16B).
// 64B-unit rows: bank_base=(row&1)*16+chunk*4 -> XOR key = row bits{1,2}: slot = lc ^ ((row>>1)&3),
// applied on the GLOBAL source side so linear gl_lds writes land swizzled (r5-verified).
// Per K-tile: 4 phases; phase = {4-8 ds_read_b128 || stage one 16KB unit of tile t+1 (2 gl_lds/lane),
// barrier, lgkmcnt(0), setprio(1), 16 MFMA, setprio(0), barrier}. vmcnt(4) only after P1 / P3:
//   unit timeline (2 loads each): ...kh1(t)[P2,P3 of t-1], kh0(t+1)[P0,P1 of t] -> at P1-end
//   outstanding = 8, vmcnt(4) retires kh1(t) (staged 3-4 phases ago); at P3-end retires kh0(t+1).
// Loads never drain to 0 in the loop; tile 7 peeled (vmcnt(0) at its P1-end).
__global__ __launch_bounds__(512,2) void k_qkv(const u16* __restrict__ xnt, const u16* __restrict__ wq,
                                               const float* __restrict__ bq,
                                               u16* __restrict__ Qt, u16* __restrict__ Kt, u16* __restrict__ Vh){
  extern __shared__ __align__(16) u16 smem[];      // 131072 B = 2 x 32768-u16 K-tile buffers
  const int l0 = blockIdx.x*256, o0 = blockIdx.y*256, b = blockIdx.z;
  const int tid = threadIdx.x, wv = tid>>6, lane = tid&63, g = lane>>4, r = lane&15;
  const int wm = wv>>2, wn = wv&3;                 // 2 x 4 wave grid
  const u16* Ab = xnt + ((size_t)(b*4096 + l0))*512;
  const u16* Wb = wq  + (size_t)o0*512;
  // staging: unit = 1024 chunks (256 rows x 4 chunks); lane covers cid = j*512 + tid (j=0,1):
  // row = cid>>2, phys chunk pc = cid&3, logical chunk lc = pc ^ ((row>>1)&3) (source pre-swizzle)
  const u16 *Asrc[2], *Wsrc[2];
  int ldo[2];
#pragma unroll
  for (int j = 0; j < 2; ++j){
    const int cid = j*512 + tid;
    const int row = cid >> 2, pc = cid & 3;
    const int lc = pc ^ ((row >> 1) & 3);
    Asrc[j] = Ab + (size_t)row*512 + lc*8;
    Wsrc[j] = Wb + (size_t)row*512 + lc*8;
    ldo[j] = (j*512 + wv*64)*8;                    // wave-uniform LDS chunk base (u16)
  }
  f32x4 acc[8][4];
#pragma unroll
  for (int mt = 0; mt < 8; ++mt)
#pragma unroll
    for (int nt = 0; nt < 4; ++nt) acc[mt][nt] = (f32x4){0.f,0.f,0.f,0.f};
  const int key = (r >> 1) & 3;

#define STGU(regionu16, srcarr, koff) do { \
    u16* _d = smem + (regionu16); \
    _Pragma("unroll") \
    for (int _j = 0; _j < 2; ++_j) gl_lds16(srcarr[_j] + (koff), _d + ldo[_j]); \
  } while(0)
  // regions within buffer c: A-kh(kk) at c + kk*8192; W-kh(kk) at c + 16384 + kk*8192
#define LDA(kk, mo) do { \
    _Pragma("unroll") \
    for (int _i = 0; _i < 4; ++_i) \
      a_[_i] = *(const bf16x8*)&smem[c + (kk)*8192 + ((wm*128 + ((mo)+_i)*16 + r)*4 + (g ^ key))*8]; \
  } while(0)
#define LDW(kk) do { \
    _Pragma("unroll") \
    for (int _i = 0; _i < 4; ++_i) \
      w_[_i] = *(const bf16x8*)&smem[c + 16384 + (kk)*8192 + ((wn*64 + _i*16 + r)*4 + (g ^ key))*8]; \
  } while(0)
#define MM(mo) do { \
    __builtin_amdgcn_s_setprio(1); \
    _Pragma("unroll") \
    for (int _i = 0; _i < 4; ++_i) \
      _Pragma("unroll") \
      for (int _j = 0; _j < 4; ++_j) acc[(mo)+_i][_j] = MFMA(a_[_i], w_[_j], acc[(mo)+_i][_j]); \
    __builtin_amdgcn_s_setprio(0); \
  } while(0)
#define BAR()   do { __builtin_amdgcn_s_barrier(); __builtin_amdgcn_sched_barrier(0); } while(0)
#define LGKM0() do { asm volatile("s_waitcnt lgkmcnt(0)" ::: "memory"); __builtin_amdgcn_sched_barrier(0); } while(0)

  // prologue: stage all 4 units of tile 0 into buf0 (order: A-kh0, W-kh0, A-kh1, W-kh1)
  STGU(0,     Asrc, 0);
  STGU(16384, Wsrc, 0);
  STGU(8192,  Asrc, 32);
  STGU(24576, Wsrc, 32);
  asm volatile("s_waitcnt vmcnt(4)" ::: "memory");   // kh0 pair landed; kh1 in flight
  BAR();

  for (int t = 0; t < 7; ++t){
    const int c  = (t & 1) << 15;                  // *32768 u16
    const int nb = c ^ 32768;
    const int ko = (t + 1) * 64;
    bf16x8 a_[4], w_[4];
    // P0: kk0, mt 0-3 + W kk0; stage A-kh0(t+1)
    LDA(0, 0); LDW(0);
    STGU(nb,         Asrc, ko);
    BAR(); LGKM0();
    MM(0);
    BAR();
    // P1: kk0, mt 4-7 (W reused); stage W-kh0(t+1)
    LDA(0, 4);
    STGU(nb + 16384, Wsrc, ko);
    BAR(); LGKM0();
    MM(4);
    asm volatile("s_waitcnt vmcnt(4)" ::: "memory");  // kh1(t) landed
    BAR();
    // P2: kk1, mt 0-3 + W kk1; stage A-kh1(t+1)
    LDA(1, 0); LDW(1);
    STGU(nb + 8192,  Asrc, ko + 32);
    BAR(); LGKM0();
    MM(0);
    BAR();
    // P3: kk1, mt 4-7; stage W-kh1(t+1)
    LDA(1, 4);
    STGU(nb + 24576, Wsrc, ko + 32);
    BAR(); LGKM0();
    MM(4);
    asm volatile("s_waitcnt vmcnt(4)" ::: "memory");  // kh0(t+1) landed
    BAR();
  }
  {                                                // tile 7 (buf 1), no staging
    const int c = 32768;
    bf16x8 a_[4], w_[4];
    LDA(0, 0); LDW(0); BAR(); LGKM0(); MM(0); BAR();
    LDA(0, 4);         BAR(); LGKM0(); MM(4);
    asm volatile("s_waitcnt vmcnt(0)" ::: "memory");  // kh1(7) landed
    BAR();
    LDA(1, 0); LDW(1); BAR(); LGKM0(); MM(0); BAR();
    LDA(1, 4);         BAR(); LGKM0(); MM(4);
  }
#undef STGU
#undef LDA
#undef LDW
#undef MM
#undef BAR
#undef LGKM0

  __syncthreads();                                 // all reads done; reuse smem for epilogue
  const int t   = blockIdx.y >> 1;                 // 0=Q 1=K 2=V
  const int cp0 = (blockIdx.y & 1)*256;            // c' base within tensor
  const int h   = blockIdx.x >> 1;                 // head = l0/512
  const int lh0 = (blockIdx.x & 1)*256;            // pos base within head
  const size_t bh = (size_t)(b*8 + h);
  if (t < 2){                                      // Q/K: dst[pos=l][c'=o], bounce [l 128][o 264]
    u16* dst = (t == 0) ? Qt : Kt;
#pragma unroll
    for (int p = 0; p < 2; ++p){                   // l-half == wm
      if (wm == p){
#pragma unroll
        for (int nt = 0; nt < 4; ++nt){
          const int ol = wn*64 + nt*16 + r;
          const float bi = bq[o0 + ol];
#pragma unroll
          for (int mt = 0; mt < 8; ++mt){
            const int ll = mt*16 + g*4;            // l-local within half
#pragma unroll
            for (int rr = 0; rr < 4; ++rr) smem[(ll + rr)*264 + ol] = f2bf(acc[mt][nt][rr] + bi);
          }
        }
      }
      __syncthreads();
#pragma unroll
      for (int i = 0; i < 8; ++i){
        int v = i*512 + tid; int row = v >> 5, seg = v & 31;
        bf16x8 d = *(const bf16x8*)&smem[row*264 + seg*8];
        *(bf16x8*)(dst + (bh*512 + lh0 + p*128 + row)*512 + cp0 + seg*8) = d;
      }
      __syncthreads();
    }
  } else {                                         // V: dst[c'=o][pos=l], bounce [o 128][l 264]
#pragma unroll
    for (int p = 0; p < 2; ++p){                   // o-half == wn>>1
      if ((wn >> 1) == p){
#pragma unroll
        for (int nt = 0; nt < 4; ++nt){
          const int ol = (wn & 1)*64 + nt*16 + r;  // o-local within half
          const float bi = bq[o0 + p*128 + ol];
#pragma unroll
          for (int mt = 0; mt < 8; ++mt){
            const int ll = wm*128 + mt*16 + g*4;
            bf16x4 pk;
#pragma unroll
            for (int rr = 0; rr < 4; ++rr) pk[rr] = (short)f2bf(acc[mt][nt][rr] + bi);
            *(bf16x4*)&smem[ol*264 + ll] = pk;
          }
        }
      }
      __syncthreads();
#pragma unroll
      for (int i = 0; i < 8; ++i){
        int v = i*512 + tid; int row = v >> 5, seg = v & 31;
        bf16x8 d = *(const bf16x8*)&smem[row*264 + seg*8];
        *(bf16x8*)(Vh + (bh*512 + cp0 + p*128 + row)*512 + lh0 + seg*8) = d;
      }
      __syncthreads();
    }
  }
}

// ---------------- Kernel 4: fused attention, QBLK=128, 512 threads, 8 waves ----------------
__global__ __launch_bounds__(512,2) void k_attn(const u16* __restrict__ Qt, const u16* __restrict__ Kt,
                                                const u16* __restrict__ Vh, u16* __restrict__ At){
  extern __shared__ __align__(16) u16 smem[];      // 135168 B dynamic
  float* sMax = (float*)(smem + 65536);            // byte 131072: [q 128][wk 4]
  float* sSum = sMax + 512;                        // byte 133120: [q 128][wk 4]
  const int wgid = blockIdx.x;                     // 0..511; XCD-chunked remap (512 % 8 == 0 -> bijective)
  const int orig = (wgid & 7)*64 + (wgid >> 3);
  const int b = orig >> 5, h = (orig >> 2) & 7, q0 = (orig & 3) * 128;
  const int bh = b*8 + h;
  const int tid = threadIdx.x, wv = tid>>6, lane = tid&63, g = lane>>4, r = lane&15;
  const int wq = wv>>2, wk = wv&3;
  const size_t base = (size_t)bh * 262144;
  const u16* Qb = Qt + base + (size_t)q0*512;
  const u16* Kb = Kt + base;
  const u16* Vb = Vh + base;

  const u16* gsrc[5];
  int ldoff[5];
  {
    const int l4 = lane >> 2, pc = lane & 3;
#pragma unroll
    for (int j = 0; j < 5; ++j){
      const int i = wv*5 + j;
      const int row = ((i < 8) ? (i*16) : ((i-8)*16)) + l4;
      const u16* bp = (i < 8) ? (Qb + (size_t)row*512) : (Kb + (size_t)row*512);
      gsrc[j] = bp + ((pc ^ ((row >> 1) & 3)) * 8);
      ldoff[j] = i * 512;                          // u16 units; Q at [0,4096), K at [4096,20480)
    }
  }

  f32x4 s[4][8];
#pragma unroll
  for (int mt = 0; mt < 4; ++mt)
#pragma unroll
    for (int nt = 0; nt < 8; ++nt) s[mt][nt] = (f32x4){0.f,0.f,0.f,0.f};

  const int qswz = (g ^ ((r >> 1) & 3)) * 8;       // swizzled 16B-chunk offset within 64B row (u16)

#define STAGE_QK(bufbase, c0) do { \
    u16* _bb = (bufbase); \
    _Pragma("unroll") \
    for (int _j = 0; _j < 5; ++_j) gl_lds16(gsrc[_j] + (c0), _bb + ldoff[_j]); \
  } while(0)

#define QK_COMPUTE(bbp) do { \
    const u16* _cb = (bbp); \
    bf16x8 a_[4], kb_[8]; \
    _Pragma("unroll") \
    for (int _mt = 0; _mt < 4; ++_mt) a_[_mt] = *(const bf16x8*)&_cb[(wq*64 + _mt*16 + r)*32 + qswz]; \
    _Pragma("unroll") \
    for (int _nt = 0; _nt < 8; ++_nt) kb_[_nt] = *(const bf16x8*)&_cb[4096 + (wk*128 + _nt*16 + r)*32 + qswz]; \
    __builtin_amdgcn_s_setprio(1); \
    _Pragma("unroll") \
    for (int _mt = 0; _mt < 4; ++_mt) \
      _Pragma("unroll") \
      for (int _nt = 0; _nt < 8; ++_nt) s[_mt][_nt] = MFMA(a_[_mt], kb_[_nt], s[_mt][_nt]); \
    __builtin_amdgcn_s_setprio(0); \
  } while(0)

  // ---- Phase 1: S[q 128][k 512] = sum_c Q K^T, c-steps of 32, depth-2 pipeline over 3 buffers
  STAGE_QK(smem,         0);                       // cs=0 -> buf0
  STAGE_QK(smem + 20480, 32);                      // cs=1 -> buf1
  int bcur = 0;
  for (int cs = 0; cs < 15; ++cs){
    asm volatile("s_waitcnt vmcnt(5)" ::: "memory");   // own stage(cs) done; stage(cs+1) in flight
    __builtin_amdgcn_s_barrier();                      // all waves' stage(cs) visible; buf[(cs-1)%3] free
    __builtin_amdgcn_sched_barrier(0);
    if (cs < 14){
      int bn = bcur + 2; if (bn >= 3) bn -= 3;
      STAGE_QK(smem + bn*20480, (cs+2)*32);
    }
    QK_COMPUTE(smem + bcur*20480);
    if (++bcur == 3) bcur = 0;
  }
  asm volatile("s_waitcnt vmcnt(0)" ::: "memory");
  __builtin_amdgcn_s_barrier();
  __builtin_amdgcn_sched_barrier(0);
  QK_COMPUTE(smem + bcur*20480);                   // cs=15 (buf 0)

  // ---- softmax over k=512 (D layout: q = wq*64+mt*16+g*4+rr, k = wk*128+nt*16+r)
#pragma unroll
  for (int mt = 0; mt < 4; ++mt)
#pragma unroll
    for (int nt = 0; nt < 8; ++nt)
#pragma unroll
      for (int rr = 0; rr < 4; ++rr) s[mt][nt][rr] *= 0.125f;

  float mx[4][4];
#pragma unroll
  for (int mt = 0; mt < 4; ++mt)
#pragma unroll
    for (int rr = 0; rr < 4; ++rr){
      float m = s[mt][0][rr];
#pragma unroll
      for (int nt = 1; nt < 8; ++nt) m = fmaxf(m, s[mt][nt][rr]);
      m = fmaxf(m, __shfl_xor(m, 1, 64)); m = fmaxf(m, __shfl_xor(m, 2, 64));
      m = fmaxf(m, __shfl_xor(m, 4, 64)); m = fmaxf(m, __shfl_xor(m, 8, 64));
      mx[mt][rr] = m;
    }
  if (r == 0){
#pragma unroll
    for (int mt = 0; mt < 4; ++mt)
#pragma unroll
      for (int rr = 0; rr < 4; ++rr) sMax[(wq*64 + mt*16 + g*4 + rr)*4 + wk] = mx[mt][rr];
  }
  __syncthreads();
#pragma unroll
  for (int mt = 0; mt < 4; ++mt)
#pragma unroll
    for (int rr = 0; rr < 4; ++rr){
      float4 v = *(const float4*)&sMax[(wq*64 + mt*16 + g*4 + rr)*4];
      mx[mt][rr] = fmaxf(fmaxf(v.x, v.y), fmaxf(v.z, v.w));
    }
  float inv[4][4];
#pragma unroll
  for (int mt = 0; mt < 4; ++mt)
#pragma unroll
    for (int rr = 0; rr < 4; ++rr){
      float t = 0.f;
#pragma unroll
      for (int nt = 0; nt < 8; ++nt){
        float e = __expf(s[mt][nt][rr] - mx[mt][rr]);
        s[mt][nt][rr] = e; t += e;
      }
      t += __shfl_xor(t, 1, 64); t += __shfl_xor(t, 2, 64);
      t += __shfl_xor(t, 4, 64); t += __shfl_xor(t, 8, 64);
      inv[mt][rr] = t;                             // wave-partial sum for now
    }
  if (r == 0){
#pragma unroll
    for (int mt = 0; mt < 4; ++mt)
#pragma unroll
      for (int rr = 0; rr < 4; ++rr) sSum[(wq*64 + mt*16 + g*4 + rr)*4 + wk] = inv[mt][rr];
  }
  __syncthreads();
#pragma unroll
  for (int mt = 0; mt < 4; ++mt)
#pragma unroll
    for (int rr = 0; rr < 4; ++rr){
      float4 v = *(const float4*)&sSum[(wq*64 + mt*16 + g*4 + rr)*4];
      inv[mt][rr] = 1.f / (v.x + v.y + v.z + v.w);
    }
  // write P (bf16, chunk-swizzled ch^(q&7)) over the dead staging region
  {
    const int kx7 = r & 7, kbase = wk*16 + (r>>3);
#pragma unroll
    for (int mt = 0; mt < 4; ++mt)
#pragma unroll
      for (int rr = 0; rr < 4; ++rr){
        const int q = wq*64 + mt*16 + g*4 + rr;
        const int ro = q*512, qx = q & 7;
        const float iv = inv[mt][rr];
#pragma unroll
        for (int nt = 0; nt < 8; ++nt){
          const int ch = kbase + nt*2;             // k>>3
          smem[ro + ((ch ^ qx) * 8) + kx7] = f2bf(s[mt][nt][rr] * iv);
        }
      }
  }
  // early V prefetch: issue first fragments before the barrier so HBM latency hides under it
  const u16* Vw = Vb + (size_t)(wv*64 + r)*512 + g*8;
  bf16x8 vf[2][4];
#pragma unroll
  for (int mt = 0; mt < 4; ++mt) vf[0][mt] = *(const bf16x8*)(Vw + mt*8192);
  __syncthreads();

  // ---- Phase 2: A[c 512][q 128] = sum_k V[c][k] P[q][k]; wave owns c-range 64, barrier-free
  f32x4 o[4][8];
#pragma unroll
  for (int mt = 0; mt < 4; ++mt)
#pragma unroll
    for (int nt = 0; nt < 8; ++nt) o[mt][nt] = (f32x4){0.f,0.f,0.f,0.f};
#pragma unroll
  for (int kk = 0; kk < 16; ++kk){
    if (kk < 15){
#pragma unroll
      for (int mt = 0; mt < 4; ++mt) vf[(kk+1)&1][mt] = *(const bf16x8*)(Vw + mt*8192 + (kk+1)*32);
    }
    bf16x8 pp[8];
#pragma unroll
    for (int nt = 0; nt < 8; ++nt){
      const int q = nt*16 + r;
      pp[nt] = *(const bf16x8*)&smem[q*512 + (((kk*4 + g) ^ (r & 7)) * 8)];
    }
    __builtin_amdgcn_s_setprio(1);
#pragma unroll
    for (int mt = 0; mt < 4; ++mt)
#pragma unroll
      for (int nt = 0; nt < 8; ++nt) o[mt][nt] = MFMA(vf[kk&1][mt], pp[nt], o[mt][nt]);
    __builtin_amdgcn_s_setprio(0);
  }
  __syncthreads();                                  // all P reads done; reuse smem as At bounce

  // bounce o -> LDS [q][c] (same chunk swizzle), then coalesced copy out
#pragma unroll
  for (int mt = 0; mt < 4; ++mt){
    const int c = wv*64 + mt*16 + g*4;
    const int ch = c >> 3, cl = c & 7;
#pragma unroll
    for (int nt = 0; nt < 8; ++nt){
      const int q = nt*16 + r;
      bf16x4 pk;
#pragma unroll
      for (int rr = 0; rr < 4; ++rr) pk[rr] = (short)f2bf(o[mt][nt][rr]);
      *(bf16x4*)&smem[q*512 + ((ch ^ (r & 7)) * 8) + cl] = pk;
    }
  }
  __syncthreads();
  u16* Ad = At + ((size_t)(bh*512 + q0))*512;      // exactly this block's Q rows (in-place alias)
#pragma unroll
  for (int i = 0; i < 16; ++i){
    const int idx = tid + i*512, q = idx >> 6, ch = idx & 63;
    bf16x8 d = *(const bf16x8*)&smem[q*512 + ((ch ^ (q & 7)) * 8)];
    *(bf16x8*)(Ad + (size_t)q*512 + ch*8) = d;
  }
#undef STAGE_QK
#undef QK_COMPUTE
}

// ---------------- Kernel 5: proj GEMM (r2-proven m97-style) + f32 residual -> f32 out ----------------
__global__ __launch_bounds__(256,2) void k_proj(const u16* __restrict__ At, const u16* __restrict__ wp,
                                                const float* __restrict__ bpr, const float* __restrict__ x,
                                                float* __restrict__ out){
  __shared__ u16 smem[17408];
  u16* sA = smem;
  u16* sW = smem + 8192;
  const int l0 = blockIdx.x*128, o0 = blockIdx.y*128, b = blockIdx.z;
  const int tid = threadIdx.x, wv = tid>>6, lane = tid&63, g = lane>>4, r = lane&15;
  const int wm = wv>>1, wn = wv&1;
  const u16* Ab = At + ((size_t)(b*4096 + l0))*512;
  const u16* Wb = wp + (size_t)o0*512;
  int srow[4], scol[4];
#pragma unroll
  for (int j = 0; j < 4; ++j){
    int s = wv*256 + j*64 + lane;
    srow[j] = s >> 3;
    scol[j] = ((s & 7) ^ (srow[j] & 7)) * 8;
  }
  f32x4 acc[4][4];
#pragma unroll
  for (int mt = 0; mt < 4; ++mt)
#pragma unroll
    for (int nt = 0; nt < 4; ++nt) acc[mt][nt] = (f32x4){0.f,0.f,0.f,0.f};
  const int key = r & 7;
  for (int c0 = 0; c0 < 512; c0 += 64){
    __syncthreads();
#pragma unroll
    for (int j = 0; j < 4; ++j){
      u16* ldst = &smem[(wv*256 + j*64)*8];
      gl_lds16(Ab + (size_t)srow[j]*512 + c0 + scol[j], ldst);
      gl_lds16(Wb + (size_t)srow[j]*512 + c0 + scol[j], ldst + 8192);
    }
    __syncthreads();
#pragma unroll
    for (int half = 0; half < 2; ++half){
      bf16x8 a[4], w[4];
#pragma unroll
      for (int mt = 0; mt < 4; ++mt){ int R = wm*64 + mt*16 + r; a[mt] = *(const bf16x8*)&sA[(R*8 + ((half*4+g) ^ key))*8]; }
#pragma unroll
      for (int nt = 0; nt < 4; ++nt){ int R = wn*64 + nt*16 + r; w[nt] = *(const bf16x8*)&sW[(R*8 + ((half*4+g) ^ key))*8]; }
#pragma unroll
      for (int mt = 0; mt < 4; ++mt)
#pragma unroll
        for (int nt = 0; nt < 4; ++nt) acc[mt][nt] = MFMA(a[mt], w[nt], acc[mt][nt]);
    }
  }
  __syncthreads();
#pragma unroll
  for (int nt = 0; nt < 4; ++nt){
    const int ol = wn*64 + nt*16 + r;
    const float bi = bpr[o0 + ol];
#pragma unroll
    for (int mt = 0; mt < 4; ++mt){
      const int ll = wm*64 + mt*16 + g*4;
      bf16x4 pk;
#pragma unroll
      for (int rr = 0; rr < 4; ++rr) pk[rr] = (short)f2bf(acc[mt][nt][rr] + bi);
      *(bf16x4*)&smem[ol*136 + ll] = pk;            // LDS [o][l]
    }
  }
  __syncthreads();
#pragma unroll
  for (int i = 0; i < 16; ++i){
    int v = tid + i*256; int row = v >> 5, seg = v & 31;   // row=o-local 0..127, seg*4 = l-local
    bf16x4 d = *(const bf16x4*)&smem[row*136 + seg*4];
    const size_t gi = ((size_t)(b*512 + o0 + row))*4096 + l0 + seg*4;
    float4 xv = *(const float4*)(x + gi);
    float4 ov;
    ov.x = bf2f((u16)d[0]) + xv.x;
    ov.y = bf2f((u16)d[1]) + xv.y;
    ov.z = bf2f((u16)d[2]) + xv.z;
    ov.w = bf2f((u16)d[3]) + xv.w;
    *(float4*)(out + gi) = ov;
  }
}

extern "C" void kernel_launch(void* const* d_in, const int* in_sizes, int n_in,
                              void* d_out, int out_size, void* d_ws, size_t ws_size,
                              hipStream_t stream) {
  (void)in_sizes; (void)n_in; (void)out_size; (void)ws_size;
  const float* x     = (const float*)d_in[0];
  const float* gamma = (const float*)d_in[1];
  const float* beta  = (const float*)d_in[2];
  const float* wqkv  = (const float*)d_in[3];
  const float* bqkv  = (const float*)d_in[4];
  const float* wproj = (const float*)d_in[5];
  const float* bproj = (const float*)d_in[6];
  float* out = (float*)d_out;
  char* ws = (char*)d_ws;

  float* stats = (float*)ws;                        // 8 KB
  u16* W16  = (u16*)(ws + 8192);                    // wqkv16 (786432) + wproj16 (262144)
  u16* Wq16 = W16;
  u16* Wp16 = W16 + 786432;
  u16* Qt = (u16*)(ws + 8192 + 2097152);            // 64 MiB  [b][h][pos][c]  (becomes At in place)
  u16* Kt = Qt + (size_t)33554432;                  // 64 MiB  [b][h][pos][c]
  u16* Vh = Kt + (size_t)33554432;                  // 64 MiB  [b][h][c][pos]
  u16* At = Qt;                                     // in-place alias (see k_attn)
  u16* Xnt = (u16*)d_out;                           // bf16 staging in d_out (dead before k_proj writes)

  static bool attn_attr = false;
  if (!attn_attr){
    hipFuncSetAttribute((const void*)k_attn, hipFuncAttributeMaxDynamicSharedMemorySize, 135168);
    hipFuncSetAttribute((const void*)k_qkv,  hipFuncAttributeMaxDynamicSharedMemorySize, 131072);
    attn_attr = true;
  }

  k_gn_stats<<<512, 256, 0, stream>>>(x, stats);
  k_conv_w<<<1024, 256, 0, stream>>>(wqkv, wproj, W16);
  k_gn_t<<<dim3(64,8,16), 256, 0, stream>>>(x, stats, gamma, beta, Xnt);
  k_qkv<<<dim3(16,6,16), 512, 131072, stream>>>(Xnt, Wq16, bqkv, Qt, Kt, Vh);
  k_attn<<<512, 512, 135168, stream>>>(Qt, Kt, Vh, At);
  k_proj<<<dim3(32,4,16), 256, 0, stream>>>(At, Wp16, bproj, x, out);
}

// Round 8
// 544.028 us; speedup vs baseline: 1.0851x; 1.0680x over previous
//
#include <hip/hip_runtime.h>

typedef unsigned short u16;
typedef __attribute__((ext_vector_type(8))) short bf16x8;   // 8 bf16 = 4 VGPRs (MFMA A/B frag)
typedef __attribute__((ext_vector_type(4))) short bf16x4;
typedef __attribute__((ext_vector_type(4))) float f32x4;    // MFMA C/D frag

__device__ __forceinline__ float bf2f(u16 u){ union { unsigned int i; float f; } v; v.i = ((unsigned int)u) << 16; return v.f; }
__device__ __forceinline__ u16 f2bf(float f){ union { float f; unsigned int i; } v; v.f = f; unsigned int r = v.i + 0x7fffu + ((v.i >> 16) & 1u); return (u16)(r >> 16); }

#define MFMA(a,b,c) __builtin_amdgcn_mfma_f32_16x16x32_bf16((a),(b),(c),0,0,0)

// async global->LDS, 16B per lane. LDS dest is wave-uniform base + lane*16.
__device__ __forceinline__ void gl_lds16(const u16* g, u16* l){
  __builtin_amdgcn_global_load_lds((const __attribute__((address_space(1))) unsigned int*)g,
                                   (__attribute__((address_space(3))) unsigned int*)l, 16, 0, 0);
}

// ---------------- Kernel 1: merged GroupNorm stats + weight bf16 conversion ----------------
// blocks [0,512): stats (mean,rstd) per (b,group); blocks [512,1536): f32->bf16 weight pack.
__global__ __launch_bounds__(256) void k_prep(const float* __restrict__ x, float* __restrict__ stats,
                                              const float* __restrict__ wq, const float* __restrict__ wp,
                                              u16* __restrict__ wout){
  __shared__ float ls[4], lq[4];
  const int tid = threadIdx.x;
  if (blockIdx.x < 512){
    const int bg = blockIdx.x;
    const float4* p = (const float4*)(x + (size_t)bg * 65536);
    float s = 0.f, sq = 0.f;
    for (int i = 0; i < 64; ++i){
      float4 v = p[tid + i*256];
      s += v.x + v.y + v.z + v.w;
      sq += v.x*v.x + v.y*v.y + v.z*v.z + v.w*v.w;
    }
#pragma unroll
    for (int d = 32; d > 0; d >>= 1){ s += __shfl_down(s, d, 64); sq += __shfl_down(sq, d, 64); }
    if ((tid & 63) == 0){ ls[tid>>6] = s; lq[tid>>6] = sq; }
    __syncthreads();
    if (tid == 0){
      float S = ls[0]+ls[1]+ls[2]+ls[3];
      float Q = lq[0]+lq[1]+lq[2]+lq[3];
      float mean = S * (1.f/65536.f);
      float var  = Q * (1.f/65536.f) - mean*mean;
      stats[bg*2]   = mean;
      stats[bg*2+1] = rsqrtf(var + 1e-5f);
    }
  } else {
    const int base = ((blockIdx.x - 512)*256 + tid) * 4;     // 1024 blocks -> 1,048,576 elems
    float4 v;
    if (base < 786432) v = *(const float4*)(wq + base);
    else               v = *(const float4*)(wp + (base - 786432));
    bf16x4 o;
    o[0] = (short)f2bf(v.x); o[1] = (short)f2bf(v.y); o[2] = (short)f2bf(v.z); o[3] = (short)f2bf(v.w);
    *(bf16x4*)(wout + base) = o;
  }
}

// ---------------- Kernel 2: GN affine + transpose -> Xnt[b][l][c] (bf16) ----------------
__global__ __launch_bounds__(256) void k_gn_t(const float* __restrict__ x, const float* __restrict__ stats,
                                              const float* __restrict__ gamma, const float* __restrict__ beta,
                                              u16* __restrict__ xnt){
  __shared__ u16 tile[64*72];                      // [c][l], stride 72
  const int l0 = blockIdx.x*64, c0 = blockIdx.y*64, b = blockIdx.z;
  const int tid = threadIdx.x;
#pragma unroll
  for (int i = 0; i < 2; ++i){
    int v = tid + i*256; int cc = v >> 3, seg = v & 7;
    int c = c0 + cc;
    float mu = stats[(b*32 + (c>>4))*2], rs = stats[(b*32 + (c>>4))*2 + 1];
    float ga = gamma[c] * rs;
    float be = beta[c] - mu * ga;                  // (x-mu)*rs*g + b = x*ga + be
    const float* px = x + ((size_t)(b*512 + c))*4096 + l0 + seg*8;
    float4 a0 = *(const float4*)px;
    float4 a1 = *(const float4*)(px + 4);
    bf16x8 ov;
    ov[0]=(short)f2bf(a0.x*ga+be); ov[1]=(short)f2bf(a0.y*ga+be);
    ov[2]=(short)f2bf(a0.z*ga+be); ov[3]=(short)f2bf(a0.w*ga+be);
    ov[4]=(short)f2bf(a1.x*ga+be); ov[5]=(short)f2bf(a1.y*ga+be);
    ov[6]=(short)f2bf(a1.z*ga+be); ov[7]=(short)f2bf(a1.w*ga+be);
    *(bf16x8*)&tile[cc*72 + seg*8] = ov;
  }
  __syncthreads();
#pragma unroll
  for (int i = 0; i < 2; ++i){
    int v = tid + i*256; int ll = v >> 3, seg = v & 7;
    bf16x8 ov;
#pragma unroll
    for (int j = 0; j < 8; ++j) ov[j] = (short)tile[(seg*8 + j)*72 + ll];
    *(bf16x8*)(xnt + ((size_t)(b*4096 + l0 + ll))*512 + c0 + seg*8) = ov;
  }
}

// ---------------- Kernel 3: QKV GEMM (r2-proven m97-style: 128x128 tile, 2-barrier, BK=64) ----------------
// D[m=l][n=o] = sum_c Xnt[l][c] * Wqkv[o][c] (+bias). Writes Qt/Kt[b][h][pos][c], Vh[b][h][c][pos].
// 128B LDS rows (8 chunks), 3-bit source-side XOR swizzle key (row&7) -> conflict-free ds_read_b128.
// Measured (r2): 128.6 us, MfmaUtil 35%, conflicts 1.3M — the m97-structure ceiling; all pipelining
// grafts (BK32 counted-vmcnt r5, 256^2 1-phase r6, 256^2 8-phase r7) measured slower. Do not regress.
__global__ __launch_bounds__(256,2) void k_qkv(const u16* __restrict__ xnt, const u16* __restrict__ wq,
                                               const float* __restrict__ bq,
                                               u16* __restrict__ Qt, u16* __restrict__ Kt, u16* __restrict__ Vh){
  __shared__ u16 smem[17408];                      // 34816 B: sA[0:8192)+sW[8192:16384); epilogue reuses as 128x136
  u16* sA = smem;
  u16* sW = smem + 8192;
  const int l0 = blockIdx.x*128, o0 = blockIdx.y*128, b = blockIdx.z;
  const int tid = threadIdx.x, wv = tid>>6, lane = tid&63, g = lane>>4, r = lane&15;
  const int wm = wv>>1, wn = wv&1;
  const u16* Ab = xnt + ((size_t)(b*4096 + l0))*512;
  const u16* Wb = wq  + (size_t)o0*512;
  int srow[4], scol[4];
#pragma unroll
  for (int j = 0; j < 4; ++j){
    int s = wv*256 + j*64 + lane;
    srow[j] = s >> 3;
    scol[j] = ((s & 7) ^ (srow[j] & 7)) * 8;
  }
  f32x4 acc[4][4];
#pragma unroll
  for (int mt = 0; mt < 4; ++mt)
#pragma unroll
    for (int nt = 0; nt < 4; ++nt) acc[mt][nt] = (f32x4){0.f,0.f,0.f,0.f};

  const int key = r & 7;
  for (int c0 = 0; c0 < 512; c0 += 64){
    __syncthreads();                               // prev tile's reads done
#pragma unroll
    for (int j = 0; j < 4; ++j){
      u16* ldst = &smem[(wv*256 + j*64)*8];        // wave-uniform
      gl_lds16(Ab + (size_t)srow[j]*512 + c0 + scol[j], ldst);
      gl_lds16(Wb + (size_t)srow[j]*512 + c0 + scol[j], ldst + 8192);
    }
    __syncthreads();                               // staged data visible
#pragma unroll
    for (int half = 0; half < 2; ++half){
      bf16x8 a[4], w[4];
#pragma unroll
      for (int mt = 0; mt < 4; ++mt){ int R = wm*64 + mt*16 + r; a[mt] = *(const bf16x8*)&sA[(R*8 + ((half*4+g) ^ key))*8]; }
#pragma unroll
      for (int nt = 0; nt < 4; ++nt){ int R = wn*64 + nt*16 + r; w[nt] = *(const bf16x8*)&sW[(R*8 + ((half*4+g) ^ key))*8]; }
#pragma unroll
      for (int mt = 0; mt < 4; ++mt)
#pragma unroll
        for (int nt = 0; nt < 4; ++nt) acc[mt][nt] = MFMA(a[mt], w[nt], acc[mt][nt]);
    }
  }
  __syncthreads();                                 // last tile's reads done; reuse smem for epilogue
  const int t   = blockIdx.y >> 2;                 // 0=Q 1=K 2=V
  const int cp0 = (blockIdx.y & 3)*128;            // c' base within tensor
  const int h   = blockIdx.x >> 2;                 // head = l0/512
  const int lh0 = (blockIdx.x & 3)*128;            // pos base within head
#pragma unroll
  for (int nt = 0; nt < 4; ++nt){
    const int ol = wn*64 + nt*16 + r;              // o local (= c')
    const float bi = bq[o0 + ol];
#pragma unroll
    for (int mt = 0; mt < 4; ++mt){
      const int ll = wm*64 + mt*16 + g*4;          // l local (D rows, 4 consecutive)
      if (t == 2){                                 // V: LDS [o][l]
        bf16x4 pk;
#pragma unroll
        for (int rr = 0; rr < 4; ++rr) pk[rr] = (short)f2bf(acc[mt][nt][rr] + bi);
        *(bf16x4*)&smem[ol*136 + ll] = pk;
      } else {                                     // Q/K: LDS [l][o] (transpose)
#pragma unroll
        for (int rr = 0; rr < 4; ++rr) smem[(ll + rr)*136 + ol] = f2bf(acc[mt][nt][rr] + bi);
      }
    }
  }
  __syncthreads();
  const size_t bh = (size_t)(b*8 + h);
  u16* dst = (t == 0) ? Qt : Kt;
#pragma unroll
  for (int i = 0; i < 8; ++i){
    int v = tid + i*256; int row = v >> 4, seg = v & 15;
    bf16x8 d = *(const bf16x8*)&smem[row*136 + seg*8];
    if (t == 2){
      *(bf16x8*)(Vh + (bh*512 + cp0 + row)*512 + lh0 + seg*8) = d;      // Vh[b][h][c'][pos]
    } else {
      *(bf16x8*)(dst + (bh*512 + lh0 + row)*512 + cp0 + seg*8) = d;     // Qt/Kt[b][h][pos][c']
    }
  }
}

// ---------------- Kernel 4: fused attention, QBLK=128, 512 threads, 8 waves ----------------
// Grid: 1D 512, XCD-chunked swizzle so the 4 q-tiles of each (b,h) land on one XCD (K/V L2 reuse).
// Phase 1: K[512][32]+Q[128][32] c-step tiles in LDS, 3 buffers x 40KB, depth-2 prefetch with
// counted s_waitcnt vmcnt(5) + raw s_barrier. 16B chunks XOR-swizzled with key (row>>1)&3 on the
// GLOBAL source side (64B rows: bank_base = (row&1)*16 + chunk*4 -> key must be row bits {1,2}).
// P[128][512] bf16 lives in LDS (128KB, aliases dead staging buffers), chunk swizzle ch^(q&7).
// Phase 2: V streamed global->reg (per-wave-exclusive c-range 64), barrier-free k-loop; first
// V fragments issued before the softmax-exit barrier.
__global__ __launch_bounds__(512,2) void k_attn(const u16* __restrict__ Qt, const u16* __restrict__ Kt,
                                                const u16* __restrict__ Vh, u16* __restrict__ At){
  extern __shared__ __align__(16) u16 smem[];      // 135168 B dynamic
  float* sMax = (float*)(smem + 65536);            // byte 131072: [q 128][wk 4]
  float* sSum = sMax + 512;                        // byte 133120: [q 128][wk 4]
  const int wgid = blockIdx.x;                     // 0..511; XCD-chunked remap (512 % 8 == 0 -> bijective)
  const int orig = (wgid & 7)*64 + (wgid >> 3);
  const int b = orig >> 5, h = (orig >> 2) & 7, q0 = (orig & 3) * 128;
  const int bh = b*8 + h;
  const int tid = threadIdx.x, wv = tid>>6, lane = tid&63, g = lane>>4, r = lane&15;
  const int wq = wv>>2, wk = wv&3;
  const size_t base = (size_t)bh * 262144;
  const u16* Qb = Qt + base + (size_t)q0*512;
  const u16* Kb = Kt + base;
  const u16* Vb = Vh + base;

  const u16* gsrc[5];
  int ldoff[5];
  {
    const int l4 = lane >> 2, pc = lane & 3;
#pragma unroll
    for (int j = 0; j < 5; ++j){
      const int i = wv*5 + j;
      const int row = ((i < 8) ? (i*16) : ((i-8)*16)) + l4;
      const u16* bp = (i < 8) ? (Qb + (size_t)row*512) : (Kb + (size_t)row*512);
      gsrc[j] = bp + ((pc ^ ((row >> 1) & 3)) * 8);
      ldoff[j] = i * 512;                          // u16 units; Q at [0,4096), K at [4096,20480)
    }
  }

  f32x4 s[4][8];
#pragma unroll
  for (int mt = 0; mt < 4; ++mt)
#pragma unroll
    for (int nt = 0; nt < 8; ++nt) s[mt][nt] = (f32x4){0.f,0.f,0.f,0.f};

  const int qswz = (g ^ ((r >> 1) & 3)) * 8;       // swizzled 16B-chunk offset within 64B row (u16)

#define STAGE_QK(bufbase, c0) do { \
    u16* _bb = (bufbase); \
    _Pragma("unroll") \
    for (int _j = 0; _j < 5; ++_j) gl_lds16(gsrc[_j] + (c0), _bb + ldoff[_j]); \
  } while(0)

#define QK_COMPUTE(bbp) do { \
    const u16* _cb = (bbp); \
    bf16x8 a_[4], kb_[8]; \
    _Pragma("unroll") \
    for (int _mt = 0; _mt < 4; ++_mt) a_[_mt] = *(const bf16x8*)&_cb[(wq*64 + _mt*16 + r)*32 + qswz]; \
    _Pragma("unroll") \
    for (int _nt = 0; _nt < 8; ++_nt) kb_[_nt] = *(const bf16x8*)&_cb[4096 + (wk*128 + _nt*16 + r)*32 + qswz]; \
    __builtin_amdgcn_s_setprio(1); \
    _Pragma("unroll") \
    for (int _mt = 0; _mt < 4; ++_mt) \
      _Pragma("unroll") \
      for (int _nt = 0; _nt < 8; ++_nt) s[_mt][_nt] = MFMA(a_[_mt], kb_[_nt], s[_mt][_nt]); \
    __builtin_amdgcn_s_setprio(0); \
  } while(0)

  // ---- Phase 1: S[q 128][k 512] = sum_c Q K^T, c-steps of 32, depth-2 pipeline over 3 buffers
  STAGE_QK(smem,         0);                       // cs=0 -> buf0
  STAGE_QK(smem + 20480, 32);                      // cs=1 -> buf1
  int bcur = 0;
  for (int cs = 0; cs < 15; ++cs){
    asm volatile("s_waitcnt vmcnt(5)" ::: "memory");   // own stage(cs) done; stage(cs+1) in flight
    __builtin_amdgcn_s_barrier();                      // all waves' stage(cs) visible; buf[(cs-1)%3] free
    __builtin_amdgcn_sched_barrier(0);
    if (cs < 14){
      int bn = bcur + 2; if (bn >= 3) bn -= 3;
      STAGE_QK(smem + bn*20480, (cs+2)*32);
    }
    QK_COMPUTE(smem + bcur*20480);
    if (++bcur == 3) bcur = 0;
  }
  asm volatile("s_waitcnt vmcnt(0)" ::: "memory");
  __builtin_amdgcn_s_barrier();
  __builtin_amdgcn_sched_barrier(0);
  QK_COMPUTE(smem + bcur*20480);                   // cs=15 (buf 0)

  // ---- softmax over k=512 (D layout: q = wq*64+mt*16+g*4+rr, k = wk*128+nt*16+r)
#pragma unroll
  for (int mt = 0; mt < 4; ++mt)
#pragma unroll
    for (int nt = 0; nt < 8; ++nt)
#pragma unroll
      for (int rr = 0; rr < 4; ++rr) s[mt][nt][rr] *= 0.125f;

  float mx[4][4];
#pragma unroll
  for (int mt = 0; mt < 4; ++mt)
#pragma unroll
    for (int rr = 0; rr < 4; ++rr){
      float m = s[mt][0][rr];
#pragma unroll
      for (int nt = 1; nt < 8; ++nt) m = fmaxf(m, s[mt][nt][rr]);
      m = fmaxf(m, __shfl_xor(m, 1, 64)); m = fmaxf(m, __shfl_xor(m, 2, 64));
      m = fmaxf(m, __shfl_xor(m, 4, 64)); m = fmaxf(m, __shfl_xor(m, 8, 64));
      mx[mt][rr] = m;
    }
  if (r == 0){
#pragma unroll
    for (int mt = 0; mt < 4; ++mt)
#pragma unroll
      for (int rr = 0; rr < 4; ++rr) sMax[(wq*64 + mt*16 + g*4 + rr)*4 + wk] = mx[mt][rr];
  }
  __syncthreads();
#pragma unroll
  for (int mt = 0; mt < 4; ++mt)
#pragma unroll
    for (int rr = 0; rr < 4; ++rr){
      float4 v = *(const float4*)&sMax[(wq*64 + mt*16 + g*4 + rr)*4];
      mx[mt][rr] = fmaxf(fmaxf(v.x, v.y), fmaxf(v.z, v.w));
    }
  float inv[4][4];
#pragma unroll
  for (int mt = 0; mt < 4; ++mt)
#pragma unroll
    for (int rr = 0; rr < 4; ++rr){
      float t = 0.f;
#pragma unroll
      for (int nt = 0; nt < 8; ++nt){
        float e = __expf(s[mt][nt][rr] - mx[mt][rr]);
        s[mt][nt][rr] = e; t += e;
      }
      t += __shfl_xor(t, 1, 64); t += __shfl_xor(t, 2, 64);
      t += __shfl_xor(t, 4, 64); t += __shfl_xor(t, 8, 64);
      inv[mt][rr] = t;                             // wave-partial sum for now
    }
  if (r == 0){
#pragma unroll
    for (int mt = 0; mt < 4; ++mt)
#pragma unroll
      for (int rr = 0; rr < 4; ++rr) sSum[(wq*64 + mt*16 + g*4 + rr)*4 + wk] = inv[mt][rr];
  }
  __syncthreads();
#pragma unroll
  for (int mt = 0; mt < 4; ++mt)
#pragma unroll
    for (int rr = 0; rr < 4; ++rr){
      float4 v = *(const float4*)&sSum[(wq*64 + mt*16 + g*4 + rr)*4];
      inv[mt][rr] = 1.f / (v.x + v.y + v.z + v.w);
    }
  // write P (bf16, chunk-swizzled ch^(q&7)) over the dead staging region
  {
    const int kx7 = r & 7, kbase = wk*16 + (r>>3);
#pragma unroll
    for (int mt = 0; mt < 4; ++mt)
#pragma unroll
      for (int rr = 0; rr < 4; ++rr){
        const int q = wq*64 + mt*16 + g*4 + rr;
        const int ro = q*512, qx = q & 7;
        const float iv = inv[mt][rr];
#pragma unroll
        for (int nt = 0; nt < 8; ++nt){
          const int ch = kbase + nt*2;             // k>>3
          smem[ro + ((ch ^ qx) * 8) + kx7] = f2bf(s[mt][nt][rr] * iv);
        }
      }
  }
  // early V prefetch: issue first fragments before the barrier so HBM latency hides under it
  const u16* Vw = Vb + (size_t)(wv*64 + r)*512 + g*8;
  bf16x8 vf[2][4];
#pragma unroll
  for (int mt = 0; mt < 4; ++mt) vf[0][mt] = *(const bf16x8*)(Vw + mt*8192);
  __syncthreads();

  // ---- Phase 2: A[c 512][q 128] = sum_k V[c][k] P[q][k]; wave owns c-range 64, barrier-free
  f32x4 o[4][8];
#pragma unroll
  for (int mt = 0; mt < 4; ++mt)
#pragma unroll
    for (int nt = 0; nt < 8; ++nt) o[mt][nt] = (f32x4){0.f,0.f,0.f,0.f};
#pragma unroll
  for (int kk = 0; kk < 16; ++kk){
    if (kk < 15){
#pragma unroll
      for (int mt = 0; mt < 4; ++mt) vf[(kk+1)&1][mt] = *(const bf16x8*)(Vw + mt*8192 + (kk+1)*32);
    }
    bf16x8 pp[8];
#pragma unroll
    for (int nt = 0; nt < 8; ++nt){
      const int q = nt*16 + r;
      pp[nt] = *(const bf16x8*)&smem[q*512 + (((kk*4 + g) ^ (r & 7)) * 8)];
    }
    __builtin_amdgcn_s_setprio(1);
#pragma unroll
    for (int mt = 0; mt < 4; ++mt)
#pragma unroll
      for (int nt = 0; nt < 8; ++nt) o[mt][nt] = MFMA(vf[kk&1][mt], pp[nt], o[mt][nt]);
    __builtin_amdgcn_s_setprio(0);
  }
  __syncthreads();                                  // all P reads done; reuse smem as At bounce

  // bounce o -> LDS [q][c] (same chunk swizzle), then coalesced copy out
#pragma unroll
  for (int mt = 0; mt < 4; ++mt){
    const int c = wv*64 + mt*16 + g*4;
    const int ch = c >> 3, cl = c & 7;
#pragma unroll
    for (int nt = 0; nt < 8; ++nt){
      const int q = nt*16 + r;
      bf16x4 pk;
#pragma unroll
      for (int rr = 0; rr < 4; ++rr) pk[rr] = (short)f2bf(o[mt][nt][rr]);
      *(bf16x4*)&smem[q*512 + ((ch ^ (r & 7)) * 8) + cl] = pk;
    }
  }
  __syncthreads();
  u16* Ad = At + ((size_t)(bh*512 + q0))*512;      // exactly this block's Q rows (in-place alias)
#pragma unroll
  for (int i = 0; i < 16; ++i){
    const int idx = tid + i*512, q = idx >> 6, ch = idx & 63;
    bf16x8 d = *(const bf16x8*)&smem[q*512 + ((ch ^ (q & 7)) * 8)];
    *(bf16x8*)(Ad + (size_t)q*512 + ch*8) = d;
  }
#undef STAGE_QK
#undef QK_COMPUTE
}

// ---------------- Kernel 5: proj GEMM (r2-proven m97-style) + f32 residual -> f32 out ----------------
__global__ __launch_bounds__(256,2) void k_proj(const u16* __restrict__ At, const u16* __restrict__ wp,
                                                const float* __restrict__ bpr, const float* __restrict__ x,
                                                float* __restrict__ out){
  __shared__ u16 smem[17408];
  u16* sA = smem;
  u16* sW = smem + 8192;
  const int l0 = blockIdx.x*128, o0 = blockIdx.y*128, b = blockIdx.z;
  const int tid = threadIdx.x, wv = tid>>6, lane = tid&63, g = lane>>4, r = lane&15;
  const int wm = wv>>1, wn = wv&1;
  const u16* Ab = At + ((size_t)(b*4096 + l0))*512;
  const u16* Wb = wp + (size_t)o0*512;
  int srow[4], scol[4];
#pragma unroll
  for (int j = 0; j < 4; ++j){
    int s = wv*256 + j*64 + lane;
    srow[j] = s >> 3;
    scol[j] = ((s & 7) ^ (srow[j] & 7)) * 8;
  }
  f32x4 acc[4][4];
#pragma unroll
  for (int mt = 0; mt < 4; ++mt)
#pragma unroll
    for (int nt = 0; nt < 4; ++nt) acc[mt][nt] = (f32x4){0.f,0.f,0.f,0.f};
  const int key = r & 7;
  for (int c0 = 0; c0 < 512; c0 += 64){
    __syncthreads();
#pragma unroll
    for (int j = 0; j < 4; ++j){
      u16* ldst = &smem[(wv*256 + j*64)*8];
      gl_lds16(Ab + (size_t)srow[j]*512 + c0 + scol[j], ldst);
      gl_lds16(Wb + (size_t)srow[j]*512 + c0 + scol[j], ldst + 8192);
    }
    __syncthreads();
#pragma unroll
    for (int half = 0; half < 2; ++half){
      bf16x8 a[4], w[4];
#pragma unroll
      for (int mt = 0; mt < 4; ++mt){ int R = wm*64 + mt*16 + r; a[mt] = *(const bf16x8*)&sA[(R*8 + ((half*4+g) ^ key))*8]; }
#pragma unroll
      for (int nt = 0; nt < 4; ++nt){ int R = wn*64 + nt*16 + r; w[nt] = *(const bf16x8*)&sW[(R*8 + ((half*4+g) ^ key))*8]; }
#pragma unroll
      for (int mt = 0; mt < 4; ++mt)
#pragma unroll
        for (int nt = 0; nt < 4; ++nt) acc[mt][nt] = MFMA(a[mt], w[nt], acc[mt][nt]);
    }
  }
  __syncthreads();
#pragma unroll
  for (int nt = 0; nt < 4; ++nt){
    const int ol = wn*64 + nt*16 + r;
    const float bi = bpr[o0 + ol];
#pragma unroll
    for (int mt = 0; mt < 4; ++mt){
      const int ll = wm*64 + mt*16 + g*4;
      bf16x4 pk;
#pragma unroll
      for (int rr = 0; rr < 4; ++rr) pk[rr] = (short)f2bf(acc[mt][nt][rr] + bi);
      *(bf16x4*)&smem[ol*136 + ll] = pk;            // LDS [o][l]
    }
  }
  __syncthreads();
#pragma unroll
  for (int i = 0; i < 16; ++i){
    int v = tid + i*256; int row = v >> 5, seg = v & 31;   // row=o-local 0..127, seg*4 = l-local
    bf16x4 d = *(const bf16x4*)&smem[row*136 + seg*4];
    const size_t gi = ((size_t)(b*512 + o0 + row))*4096 + l0 + seg*4;
    float4 xv = *(const float4*)(x + gi);
    float4 ov;
    ov.x = bf2f((u16)d[0]) + xv.x;
    ov.y = bf2f((u16)d[1]) + xv.y;
    ov.z = bf2f((u16)d[2]) + xv.z;
    ov.w = bf2f((u16)d[3]) + xv.w;
    *(float4*)(out + gi) = ov;
  }
}

extern "C" void kernel_launch(void* const* d_in, const int* in_sizes, int n_in,
                              void* d_out, int out_size, void* d_ws, size_t ws_size,
                              hipStream_t stream) {
  (void)in_sizes; (void)n_in; (void)out_size; (void)ws_size;
  const float* x     = (const float*)d_in[0];
  const float* gamma = (const float*)d_in[1];
  const float* beta  = (const float*)d_in[2];
  const float* wqkv  = (const float*)d_in[3];
  const float* bqkv  = (const float*)d_in[4];
  const float* wproj = (const float*)d_in[5];
  const float* bproj = (const float*)d_in[6];
  float* out = (float*)d_out;
  char* ws = (char*)d_ws;

  float* stats = (float*)ws;                        // 8 KB
  u16* W16  = (u16*)(ws + 8192);                    // wqkv16 (786432) + wproj16 (262144)
  u16* Wq16 = W16;
  u16* Wp16 = W16 + 786432;
  u16* Qt = (u16*)(ws + 8192 + 2097152);            // 64 MiB  [b][h][pos][c]  (becomes At in place)
  u16* Kt = Qt + (size_t)33554432;                  // 64 MiB  [b][h][pos][c]
  u16* Vh = Kt + (size_t)33554432;                  // 64 MiB  [b][h][c][pos]
  u16* At = Qt;                                     // in-place alias (see k_attn)
  u16* Xnt = (u16*)d_out;                           // bf16 staging in d_out (dead before k_proj writes)

  static bool attn_attr = false;
  if (!attn_attr){
    hipFuncSetAttribute((const void*)k_attn, hipFuncAttributeMaxDynamicSharedMemorySize, 135168);
    attn_attr = true;
  }

  k_prep<<<1536, 256, 0, stream>>>(x, stats, wqkv, wproj, W16);
  k_gn_t<<<dim3(64,8,16), 256, 0, stream>>>(x, stats, gamma, beta, Xnt);
  k_qkv<<<dim3(32,12,16), 256, 0, stream>>>(Xnt, Wq16, bqkv, Qt, Kt, Vh);
  k_attn<<<512, 512, 135168, stream>>>(Qt, Kt, Vh, At);
  k_proj<<<dim3(32,4,16), 256, 0, stream>>>(At, Wp16, bproj, x, out);
}